// Round 1
// baseline (333.283 us; speedup 1.0000x reference)
//
#include <hip/hip_runtime.h>
#include <hip/hip_bf16.h>

#define BATCH 2
#define LSEQ 4096
#define DM 256
#define NS 16
#define BL (BATCH*LSEQ)
#define CHUNK 64
#define NCHUNK (LSEQ/CHUNK)
#define NCHAIN (BATCH*DM*NS)

__device__ __forceinline__ float softplus_f(float z){
    return fmaxf(z, 0.0f) + log1pf(__expf(-fabsf(z)));
}
__device__ __forceinline__ float gelu_f(float x){
    float x3 = x*x*x;
    float t = tanhf(0.7978845608028654f*(x + 0.044715f*x3));
    return 0.5f*x*(1.0f+t);
}

// One wave per row of 256 floats; block = 4 rows.
__global__ __launch_bounds__(256) void rmsnorm_k(const float* __restrict__ in,
                                                 float* __restrict__ out){
    int lane = threadIdx.x & 63;
    int wv   = threadIdx.x >> 6;
    int row  = blockIdx.x*4 + wv;
    const float4* rin = (const float4*)(in + (size_t)row*DM);
    float4 v = rin[lane];
    float ss = v.x*v.x + v.y*v.y + v.z*v.z + v.w*v.w;
    #pragma unroll
    for (int off=32; off>=1; off>>=1) ss += __shfl_xor(ss, off, 64);
    float s = rsqrtf(ss*(1.0f/DM) + 1.1920929e-07f);
    float4 o; o.x=v.x*s; o.y=v.y*s; o.z=v.z*s; o.w=v.w*s;
    ((float4*)(out + (size_t)row*DM))[lane] = o;
}

// [8 rows x 256] @ [256 x (256 dt | 16 B | 16 C)], fused softplus+bias on dt.
__global__ __launch_bounds__(256) void gemm_dtbc_k(const float* __restrict__ xn,
                            const float* __restrict__ Wd,
                            const float* __restrict__ bd,
                            const float* __restrict__ WB,
                            const float* __restrict__ WC,
                            float* __restrict__ dt,
                            float* __restrict__ Bm,
                            float* __restrict__ Cm){
    __shared__ float xs[8][DM];
    int tid = threadIdx.x;
    int row0 = blockIdx.x*8;
    const float4* src = (const float4*)(xn + (size_t)row0*DM);
    float4* dv = (float4*)&xs[0][0];
    dv[tid]     = src[tid];
    dv[tid+256] = src[tid+256];
    __syncthreads();
    {   // dt columns: e = tid in [0,256)
        int e = tid;
        float acc[8] = {0,0,0,0,0,0,0,0};
        const float* w = Wd + e;
        #pragma unroll 4
        for (int d=0; d<DM; ++d){
            float wv = w[(size_t)d*DM];
            #pragma unroll
            for (int r=0;r<8;++r) acc[r] = fmaf(xs[r][d], wv, acc[r]);
        }
        float bias = bd[e];
        #pragma unroll
        for (int r=0;r<8;++r)
            dt[(size_t)(row0+r)*DM + e] = softplus_f(acc[r] + bias);
    }
    if (tid < 32){  // B (tid<16) and C (16..31) columns
        int n = tid & 15;
        const float* w = ((tid < 16) ? WB : WC) + n;
        float acc[8] = {0,0,0,0,0,0,0,0};
        #pragma unroll 4
        for (int d=0; d<DM; ++d){
            float wv = w[(size_t)d*NS];
            #pragma unroll
            for (int r=0;r<8;++r) acc[r] = fmaf(xs[r][d], wv, acc[r]);
        }
        float* outp = (tid < 16) ? Bm : Cm;
        #pragma unroll
        for (int r=0;r<8;++r) outp[(size_t)(row0+r)*NS + n] = acc[r];
    }
}

// gelu(y) @ W_mix + b_mix
__global__ __launch_bounds__(256) void gemm_mix_k(const float* __restrict__ y,
                           const float* __restrict__ Wm,
                           const float* __restrict__ bm,
                           float* __restrict__ out){
    __shared__ float xs[8][DM];
    int tid = threadIdx.x;
    int row0 = blockIdx.x*8;
    const float4* src = (const float4*)(y + (size_t)row0*DM);
    float4* dv = (float4*)&xs[0][0];
    float4 v0 = src[tid], v1 = src[tid+256];
    v0.x = gelu_f(v0.x); v0.y = gelu_f(v0.y); v0.z = gelu_f(v0.z); v0.w = gelu_f(v0.w);
    v1.x = gelu_f(v1.x); v1.y = gelu_f(v1.y); v1.z = gelu_f(v1.z); v1.w = gelu_f(v1.w);
    dv[tid]     = v0;
    dv[tid+256] = v1;
    __syncthreads();
    int e = tid;
    float acc[8] = {0,0,0,0,0,0,0,0};
    const float* w = Wm + e;
    #pragma unroll 4
    for (int d=0; d<DM; ++d){
        float wv = w[(size_t)d*DM];
        #pragma unroll
        for (int r=0;r<8;++r) acc[r] = fmaf(xs[r][d], wv, acc[r]);
    }
    float bias = bm[e];
    #pragma unroll
    for (int r=0;r<8;++r) out[(size_t)(row0+r)*DM + e] = acc[r] + bias;
}

// Phase 1: per-chunk composed (Ap, Bp) for each (b,d,n) chain.
// block: 256 threads = 16 d's x 16 n's. grid: (NCHUNK, BATCH*DM/16)
__global__ __launch_bounds__(256) void scan_p1(const float* __restrict__ xn,
                        const float* __restrict__ dt,
                        const float* __restrict__ Bm,
                        const float* __restrict__ A,
                        float* __restrict__ cA, float* __restrict__ cB){
    int n  = threadIdx.x & 15;
    int dg = threadIdx.x >> 4;
    int c  = blockIdx.x;
    int bd = blockIdx.y;
    int b  = bd >> 4;
    int d  = ((bd & 15) << 4) + dg;
    float Adn = A[d*NS + n];
    size_t base  = ((size_t)b*LSEQ + (size_t)c*CHUNK)*DM + d;
    size_t baseB = ((size_t)b*LSEQ + (size_t)c*CHUNK)*NS + n;
    float Ap = 1.0f, Bp = 0.0f;
    for (int t=0;t<CHUNK;++t){
        float dtv = dt[base + (size_t)t*DM];
        float xv  = xn[base + (size_t)t*DM];
        float bmv = Bm[baseB + (size_t)t*NS];
        float a  = __expf(dtv*Adn);
        float bb = dtv*bmv*xv;
        Ap *= a;
        Bp = fmaf(a, Bp, bb);
    }
    int chain = (b*DM + d)*NS + n;
    cA[(size_t)c*NCHAIN + chain] = Ap;
    cB[(size_t)c*NCHAIN + chain] = Bp;
}

// Phase 2: sequential scan across chunks (tiny).
__global__ __launch_bounds__(256) void scan_p2(const float* __restrict__ cA,
                        const float* __restrict__ cB,
                        float* __restrict__ hin){
    int chain = blockIdx.x*256 + threadIdx.x;
    float h = 0.0f;
    for (int c=0;c<NCHUNK;++c){
        hin[(size_t)c*NCHAIN + chain] = h;
        h = fmaf(cA[(size_t)c*NCHAIN + chain], h, cB[(size_t)c*NCHAIN + chain]);
    }
}

// Phase 3: re-run within chunk with correct h_in; y = sum_n h*C + D_skip*x
__global__ __launch_bounds__(256) void scan_p3(const float* __restrict__ xn,
                        const float* __restrict__ dt,
                        const float* __restrict__ Bm,
                        const float* __restrict__ Cm,
                        const float* __restrict__ A,
                        const float* __restrict__ Dsk,
                        const float* __restrict__ hin,
                        float* __restrict__ y){
    int n  = threadIdx.x & 15;
    int dg = threadIdx.x >> 4;
    int c  = blockIdx.x;
    int bd = blockIdx.y;
    int b  = bd >> 4;
    int d  = ((bd & 15) << 4) + dg;
    float Adn = A[d*NS + n];
    float dsk = Dsk[d];
    int chain = (b*DM + d)*NS + n;
    float h = hin[(size_t)c*NCHAIN + chain];
    size_t base  = ((size_t)b*LSEQ + (size_t)c*CHUNK)*DM + d;
    size_t baseB = ((size_t)b*LSEQ + (size_t)c*CHUNK)*NS + n;
    for (int t=0;t<CHUNK;++t){
        float dtv = dt[base + (size_t)t*DM];
        float xv  = xn[base + (size_t)t*DM];
        float bmv = Bm[baseB + (size_t)t*NS];
        float cmv = Cm[baseB + (size_t)t*NS];
        float a  = __expf(dtv*Adn);
        float bb = dtv*bmv*xv;
        h = fmaf(a, h, bb);
        float p = h * cmv;
        p += __shfl_xor(p, 1, 64);
        p += __shfl_xor(p, 2, 64);
        p += __shfl_xor(p, 4, 64);
        p += __shfl_xor(p, 8, 64);
        if (n == 0){
            y[base + (size_t)t*DM] = p + dsk*xv;
        }
    }
}

extern "C" void kernel_launch(void* const* d_in, const int* in_sizes, int n_in,
                              void* d_out, int out_size, void* d_ws, size_t ws_size,
                              hipStream_t stream) {
    const float* x  = (const float*)d_in[0];
    const float* A  = (const float*)d_in[1];
    const float* Wd = (const float*)d_in[2];
    const float* bd = (const float*)d_in[3];
    const float* WB = (const float*)d_in[4];
    const float* WC = (const float*)d_in[5];
    const float* Ds = (const float*)d_in[6];
    const float* Wm = (const float*)d_in[7];
    const float* bm = (const float*)d_in[8];
    float* out = (float*)d_out;

    float* ws  = (float*)d_ws;
    float* xn  = ws;                                  // BL*DM
    float* dt  = xn  + (size_t)BL*DM;                 // BL*DM
    float* yb  = dt  + (size_t)BL*DM;                 // BL*DM
    float* hb  = yb  + (size_t)BL*DM;                 // BL*DM
    float* Bmb = hb  + (size_t)BL*DM;                 // BL*NS
    float* Cmb = Bmb + (size_t)BL*NS;                 // BL*NS
    float* cA  = Cmb + (size_t)BL*NS;                 // NCHUNK*NCHAIN
    float* cB  = cA  + (size_t)NCHUNK*NCHAIN;         // NCHUNK*NCHAIN
    float* hin = cB  + (size_t)NCHUNK*NCHAIN;         // NCHUNK*NCHAIN

    const float* hsrc = x;
    for (int l=0; l<2; ++l){
        rmsnorm_k<<<BL/4, 256, 0, stream>>>(hsrc, xn);
        gemm_dtbc_k<<<BL/8, 256, 0, stream>>>(xn, Wd + (size_t)l*DM*DM, bd + (size_t)l*DM,
                                              WB + (size_t)l*DM*NS, WC + (size_t)l*DM*NS,
                                              dt, Bmb, Cmb);
        dim3 g1(NCHUNK, BATCH*DM/16);
        scan_p1<<<g1, 256, 0, stream>>>(xn, dt, Bmb, A + (size_t)l*DM*NS, cA, cB);
        scan_p2<<<NCHAIN/256, 256, 0, stream>>>(cA, cB, hin);
        scan_p3<<<g1, 256, 0, stream>>>(xn, dt, Bmb, Cmb, A + (size_t)l*DM*NS,
                                        Ds + (size_t)l*DM, hin, yb);
        gemm_mix_k<<<BL/8, 256, 0, stream>>>(yb, Wm + (size_t)l*DM*DM, bm + (size_t)l*DM, hb);
        hsrc = hb;
    }
    rmsnorm_k<<<BL/4, 256, 0, stream>>>(hb, out);
}

// Round 2
// 316.517 us; speedup vs baseline: 1.0530x; 1.0530x over previous
//
#include <hip/hip_runtime.h>
#include <hip/hip_bf16.h>

#define BATCH 2
#define LSEQ 4096
#define DM 256
#define NS 16
#define BL (BATCH*LSEQ)
#define CHUNK 32
#define NCHUNK (LSEQ/CHUNK)     // 128
#define NCHAIN (BATCH*DM*NS)    // 8192
#define XS_STRIDE 20
#define LOG2E 1.4426950408889634f

__device__ __forceinline__ float softplus_f(float z){
    return fmaxf(z, 0.0f) + log1pf(__expf(-fabsf(z)));
}
__device__ __forceinline__ float gelu_f(float x){
    float u = 0.7978845608028654f*(x + 0.044715f*x*x*x);
    float e = __builtin_amdgcn_exp2f(2.0f*LOG2E*u);
    float th = 1.0f - 2.0f*__builtin_amdgcn_rcpf(e + 1.0f);
    return 0.5f*x*(1.0f + th);
}

__global__ __launch_bounds__(256) void rmsnorm_k(const float* __restrict__ in,
                                                 float* __restrict__ out){
    int lane = threadIdx.x & 63;
    int wv   = threadIdx.x >> 6;
    int row  = blockIdx.x*4 + wv;
    const float4* rin = (const float4*)(in + (size_t)row*DM);
    float4 v = rin[lane];
    float ss = v.x*v.x + v.y*v.y + v.z*v.z + v.w*v.w;
    #pragma unroll
    for (int off=32; off>=1; off>>=1) ss += __shfl_xor(ss, off, 64);
    float s = rsqrtf(ss*(1.0f/DM) + 1.1920929e-07f);
    float4 o; o.x=v.x*s; o.y=v.y*s; o.z=v.z*s; o.w=v.w*s;
    ((float4*)(out + (size_t)row*DM))[lane] = o;
}

#define FMA16() do { \
        const float4* xp = (const float4*)&xs[d*XS_STRIDE]; \
        float4 x0 = xp[0], x1 = xp[1], x2 = xp[2], x3 = xp[3]; \
        acc[0]  = fmaf(x0.x, w, acc[0]);  acc[1]  = fmaf(x0.y, w, acc[1]); \
        acc[2]  = fmaf(x0.z, w, acc[2]);  acc[3]  = fmaf(x0.w, w, acc[3]); \
        acc[4]  = fmaf(x1.x, w, acc[4]);  acc[5]  = fmaf(x1.y, w, acc[5]); \
        acc[6]  = fmaf(x1.z, w, acc[6]);  acc[7]  = fmaf(x1.w, w, acc[7]); \
        acc[8]  = fmaf(x2.x, w, acc[8]);  acc[9]  = fmaf(x2.y, w, acc[9]); \
        acc[10] = fmaf(x2.z, w, acc[10]); acc[11] = fmaf(x2.w, w, acc[11]); \
        acc[12] = fmaf(x3.x, w, acc[12]); acc[13] = fmaf(x3.y, w, acc[13]); \
        acc[14] = fmaf(x3.z, w, acc[14]); acc[15] = fmaf(x3.w, w, acc[15]); \
    } while(0)

__global__ __launch_bounds__(320) void gemm_dtbc_k(const float* __restrict__ xn,
                            const float* __restrict__ Wd,
                            const float* __restrict__ bd,
                            const float* __restrict__ WB,
                            const float* __restrict__ WC,
                            float* __restrict__ dt,
                            float* __restrict__ Bm,
                            float* __restrict__ Cm){
    __shared__ float xs[DM*XS_STRIDE];
    int t = threadIdx.x;
    int row0 = blockIdx.x*16;
    if (t < 256){
        float v[16];
        #pragma unroll
        for (int r=0;r<16;++r) v[r] = xn[(size_t)(row0+r)*DM + t];
        float4* p = (float4*)&xs[t*XS_STRIDE];
        #pragma unroll
        for (int q=0;q<4;++q) p[q] = make_float4(v[4*q],v[4*q+1],v[4*q+2],v[4*q+3]);
    }
    __syncthreads();
    const float* wp; int stride;
    if (t < 256){ wp = Wd + t; stride = DM; }
    else if (t < 272){ wp = WB + (t-256); stride = NS; }
    else if (t < 288){ wp = WC + (t-272); stride = NS; }
    else { wp = Wd; stride = 0; }
    float acc[16];
    #pragma unroll
    for (int r=0;r<16;++r) acc[r] = 0.0f;
    #pragma unroll 4
    for (int d=0; d<DM; ++d){
        float w = wp[(size_t)d*stride];
        FMA16();
    }
    if (t < 256){
        float bias = bd[t];
        #pragma unroll
        for (int r=0;r<16;++r)
            dt[(size_t)(row0+r)*DM + t] = softplus_f(acc[r] + bias);
    } else if (t < 272){
        int n = t - 256;
        #pragma unroll
        for (int r=0;r<16;++r) Bm[(size_t)(row0+r)*NS + n] = acc[r];
    } else if (t < 288){
        int n = t - 272;
        #pragma unroll
        for (int r=0;r<16;++r) Cm[(size_t)(row0+r)*NS + n] = acc[r];
    }
}

__global__ __launch_bounds__(256) void gemm_mix_k(const float* __restrict__ y,
                           const float* __restrict__ Wm,
                           const float* __restrict__ bm,
                           float* __restrict__ out){
    __shared__ float xs[DM*XS_STRIDE];
    int t = threadIdx.x;
    int row0 = blockIdx.x*16;
    {
        float v[16];
        #pragma unroll
        for (int r=0;r<16;++r) v[r] = gelu_f(y[(size_t)(row0+r)*DM + t]);
        float4* p = (float4*)&xs[t*XS_STRIDE];
        #pragma unroll
        for (int q=0;q<4;++q) p[q] = make_float4(v[4*q],v[4*q+1],v[4*q+2],v[4*q+3]);
    }
    __syncthreads();
    float acc[16];
    #pragma unroll
    for (int r=0;r<16;++r) acc[r] = 0.0f;
    const float* wp = Wm + t;
    #pragma unroll 4
    for (int d=0; d<DM; ++d){
        float w = wp[(size_t)d*DM];
        FMA16();
    }
    float bias = bm[t];
    #pragma unroll
    for (int r=0;r<16;++r)
        out[(size_t)(row0+r)*DM + t] = acc[r] + bias;
}

__global__ __launch_bounds__(64) void scan_p1(const float* __restrict__ xn,
                        const float* __restrict__ dt,
                        const float* __restrict__ Bmv,
                        const float* __restrict__ A,
                        float* __restrict__ cA, float* __restrict__ cB){
    __shared__ float bs[CHUNK*NS];
    int lane = threadIdx.x;
    int c = blockIdx.x, dq = blockIdx.y, b = blockIdx.z;
    int d = dq*64 + lane;
    int row0 = b*LSEQ + c*CHUNK;
    {
        const float4* src = (const float4*)(Bmv + (size_t)row0*NS);
        float4* dst = (float4*)bs;
        #pragma unroll
        for (int i=0;i<(CHUNK*NS/4)/64;++i) dst[lane + 64*i] = src[lane + 64*i];
    }
    float Alg[NS];
    {
        const float4* ap = (const float4*)(A + (size_t)d*NS);
        #pragma unroll
        for (int q=0;q<4;++q){
            float4 av = ap[q];
            Alg[4*q+0]=av.x*LOG2E; Alg[4*q+1]=av.y*LOG2E;
            Alg[4*q+2]=av.z*LOG2E; Alg[4*q+3]=av.w*LOG2E;
        }
    }
    __syncthreads();
    float Ap[NS], Bp[NS];
    #pragma unroll
    for (int n=0;n<NS;++n){ Ap[n]=1.0f; Bp[n]=0.0f; }
    for (int tt=0; tt<CHUNK; ++tt){
        float dtv = dt[(size_t)(row0+tt)*DM + d];
        float xv  = xn[(size_t)(row0+tt)*DM + d];
        float dtx = dtv*xv;
        const float4* bp4 = (const float4*)&bs[tt*NS];
        #pragma unroll
        for (int q=0;q<4;++q){
            float4 bq = bp4[q];
            float bv[4] = {bq.x, bq.y, bq.z, bq.w};
            #pragma unroll
            for (int j=0;j<4;++j){
                int n = 4*q+j;
                float a = __builtin_amdgcn_exp2f(dtv*Alg[n]);
                Ap[n] *= a;
                Bp[n] = fmaf(a, Bp[n], dtx*bv[j]);
            }
        }
    }
    size_t base = (size_t)c*NCHAIN + ((size_t)b*DM + d)*NS;
    float4* pA = (float4*)(cA + base);
    float4* pB = (float4*)(cB + base);
    #pragma unroll
    for (int q=0;q<4;++q){
        pA[q] = make_float4(Ap[4*q],Ap[4*q+1],Ap[4*q+2],Ap[4*q+3]);
        pB[q] = make_float4(Bp[4*q],Bp[4*q+1],Bp[4*q+2],Bp[4*q+3]);
    }
}

__global__ __launch_bounds__(256) void scan_p2(const float* __restrict__ cA,
                        const float* __restrict__ cB,
                        float* __restrict__ hin){
    int chain = blockIdx.x*256 + threadIdx.x;
    float h = 0.0f;
    #pragma unroll 4
    for (int c=0;c<NCHUNK;++c){
        size_t idx = (size_t)c*NCHAIN + chain;
        hin[idx] = h;
        h = fmaf(cA[idx], h, cB[idx]);
    }
}

__global__ __launch_bounds__(64) void scan_p3(const float* __restrict__ xn,
                        const float* __restrict__ dt,
                        const float* __restrict__ Bmv,
                        const float* __restrict__ Cmv,
                        const float* __restrict__ A,
                        const float* __restrict__ Dsk,
                        const float* __restrict__ hin,
                        float* __restrict__ y){
    __shared__ float bs[CHUNK*NS], cs[CHUNK*NS];
    int lane = threadIdx.x;
    int c = blockIdx.x, dq = blockIdx.y, b = blockIdx.z;
    int d = dq*64 + lane;
    int row0 = b*LSEQ + c*CHUNK;
    {
        const float4* srcB = (const float4*)(Bmv + (size_t)row0*NS);
        const float4* srcC = (const float4*)(Cmv + (size_t)row0*NS);
        float4* dstB = (float4*)bs;
        float4* dstC = (float4*)cs;
        #pragma unroll
        for (int i=0;i<(CHUNK*NS/4)/64;++i){
            dstB[lane + 64*i] = srcB[lane + 64*i];
            dstC[lane + 64*i] = srcC[lane + 64*i];
        }
    }
    float Alg[NS];
    {
        const float4* ap = (const float4*)(A + (size_t)d*NS);
        #pragma unroll
        for (int q=0;q<4;++q){
            float4 av = ap[q];
            Alg[4*q+0]=av.x*LOG2E; Alg[4*q+1]=av.y*LOG2E;
            Alg[4*q+2]=av.z*LOG2E; Alg[4*q+3]=av.w*LOG2E;
        }
    }
    float dsk = Dsk[d];
    float h[NS];
    {
        const float4* hp = (const float4*)(hin + (size_t)c*NCHAIN + ((size_t)b*DM + d)*NS);
        #pragma unroll
        for (int q=0;q<4;++q){
            float4 hv = hp[q];
            h[4*q+0]=hv.x; h[4*q+1]=hv.y; h[4*q+2]=hv.z; h[4*q+3]=hv.w;
        }
    }
    __syncthreads();
    for (int tt=0; tt<CHUNK; ++tt){
        float dtv = dt[(size_t)(row0+tt)*DM + d];
        float xv  = xn[(size_t)(row0+tt)*DM + d];
        float dtx = dtv*xv;
        float yacc = dsk*xv;
        const float4* bp4 = (const float4*)&bs[tt*NS];
        const float4* cp4 = (const float4*)&cs[tt*NS];
        #pragma unroll
        for (int q=0;q<4;++q){
            float4 bq = bp4[q];
            float4 cq = cp4[q];
            float bv[4] = {bq.x, bq.y, bq.z, bq.w};
            float cv[4] = {cq.x, cq.y, cq.z, cq.w};
            #pragma unroll
            for (int j=0;j<4;++j){
                int n = 4*q+j;
                float a = __builtin_amdgcn_exp2f(dtv*Alg[n]);
                h[n] = fmaf(a, h[n], dtx*bv[j]);
                yacc = fmaf(h[n], cv[j], yacc);
            }
        }
        y[(size_t)(row0+tt)*DM + d] = yacc;
    }
}

extern "C" void kernel_launch(void* const* d_in, const int* in_sizes, int n_in,
                              void* d_out, int out_size, void* d_ws, size_t ws_size,
                              hipStream_t stream) {
    const float* x  = (const float*)d_in[0];
    const float* A  = (const float*)d_in[1];
    const float* Wd = (const float*)d_in[2];
    const float* bd = (const float*)d_in[3];
    const float* WB = (const float*)d_in[4];
    const float* WC = (const float*)d_in[5];
    const float* Ds = (const float*)d_in[6];
    const float* Wm = (const float*)d_in[7];
    const float* bm = (const float*)d_in[8];
    float* out = (float*)d_out;

    const size_t BSZ = (size_t)BL*DM;
    const size_t CH  = (size_t)NCHUNK*NCHAIN;
    float* ws  = (float*)d_ws;
    float* b0  = ws;
    float* b1  = b0  + BSZ;
    float* b2  = b1  + BSZ;
    float* Bmb = b2  + BSZ;
    float* Cmb = Bmb + (size_t)BL*NS;
    float* cA  = Cmb + (size_t)BL*NS;
    float* cB  = cA  + CH;
    float* hin = cB  + CH;

    dim3 gs(NCHUNK, DM/64, BATCH);

    rmsnorm_k<<<BL/4, 256, 0, stream>>>(x, b0);
    gemm_dtbc_k<<<BL/16, 320, 0, stream>>>(b0, Wd, bd, WB, WC, b1, Bmb, Cmb);
    scan_p1<<<gs, 64, 0, stream>>>(b0, b1, Bmb, A, cA, cB);
    scan_p2<<<NCHAIN/256, 256, 0, stream>>>(cA, cB, hin);
    scan_p3<<<gs, 64, 0, stream>>>(b0, b1, Bmb, Cmb, A, Ds, hin, b2);
    gemm_mix_k<<<BL/16, 256, 0, stream>>>(b2, Wm, bm, b0);

    const float* A1  = A  + (size_t)DM*NS;
    const float* Wd1 = Wd + (size_t)DM*DM;
    const float* bd1 = bd + DM;
    const float* WB1 = WB + (size_t)DM*NS;
    const float* WC1 = WC + (size_t)DM*NS;
    const float* Ds1 = Ds + DM;
    const float* Wm1 = Wm + (size_t)DM*DM;
    const float* bm1 = bm + DM;
    rmsnorm_k<<<BL/4, 256, 0, stream>>>(b0, b1);
    gemm_dtbc_k<<<BL/16, 320, 0, stream>>>(b1, Wd1, bd1, WB1, WC1, b2, Bmb, Cmb);
    scan_p1<<<gs, 64, 0, stream>>>(b1, b2, Bmb, A1, cA, cB);
    scan_p2<<<NCHAIN/256, 256, 0, stream>>>(cA, cB, hin);
    scan_p3<<<gs, 64, 0, stream>>>(b1, b2, Bmb, Cmb, A1, Ds1, hin, b0);
    gemm_mix_k<<<BL/16, 256, 0, stream>>>(b0, Wm1, bm1, b1);

    rmsnorm_k<<<BL/4, 256, 0, stream>>>(b1, out);
}

// Round 3
// 235.100 us; speedup vs baseline: 1.4176x; 1.3463x over previous
//
#include <hip/hip_runtime.h>
#include <hip/hip_bf16.h>

#define BATCH 2
#define LSEQ 4096
#define DM 256
#define NS 16
#define BL (BATCH*LSEQ)
#define CHUNK 32
#define NCHUNK (LSEQ/CHUNK)     // 128
#define NCHAIN (BATCH*DM*NS)    // 8192
#define LOG2E 1.4426950408889634f

typedef _Float16 f16x8 __attribute__((ext_vector_type(8)));
typedef _Float16 f16x4 __attribute__((ext_vector_type(4)));
typedef float f32x4 __attribute__((ext_vector_type(4)));

__device__ __forceinline__ float softplus_f(float z){
    return fmaxf(z, 0.0f) + log1pf(__expf(-fabsf(z)));
}
__device__ __forceinline__ float gelu_f(float x){
    float u = 0.7978845608028654f*(x + 0.044715f*x*x*x);
    float e = __builtin_amdgcn_exp2f(2.0f*LOG2E*u);
    float th = 1.0f - 2.0f*__builtin_amdgcn_rcpf(e + 1.0f);
    return 0.5f*x*(1.0f + th);
}

// RMSNorm; optionally also emit an f16 copy for the MFMA GEMM A-operand.
__global__ __launch_bounds__(256) void rmsnorm_k(const float* __restrict__ in,
                                                 float* __restrict__ out,
                                                 _Float16* __restrict__ outh){
    int lane = threadIdx.x & 63;
    int wv   = threadIdx.x >> 6;
    int row  = blockIdx.x*4 + wv;
    const float4* rin = (const float4*)(in + (size_t)row*DM);
    float4 v = rin[lane];
    float ss = v.x*v.x + v.y*v.y + v.z*v.z + v.w*v.w;
    #pragma unroll
    for (int off=32; off>=1; off>>=1) ss += __shfl_xor(ss, off, 64);
    float s = rsqrtf(ss*(1.0f/DM) + 1.1920929e-07f);
    float4 o; o.x=v.x*s; o.y=v.y*s; o.z=v.z*s; o.w=v.w*s;
    ((float4*)(out + (size_t)row*DM))[lane] = o;
    if (outh){
        f16x4 h; h[0]=(_Float16)o.x; h[1]=(_Float16)o.y; h[2]=(_Float16)o.z; h[3]=(_Float16)o.w;
        *(f16x4*)(outh + (size_t)row*DM + lane*4) = h;
    }
}

// Pack weights (fp32 -> f16) into MFMA B-fragment order.
// frag idx t = (nt16*8 + ks)*64 + lane ; element i:
//   col = nt16*16 + (lane&15), k = ks*32 + (lane>>4)*8 + i
// blockIdx.y: 0=L0 dtbc(288 cols), 1=L0 mix(256), 2=L1 dtbc, 3=L1 mix
__global__ __launch_bounds__(256) void pack_w_k(const float* __restrict__ Wd,
                         const float* __restrict__ WB,
                         const float* __restrict__ WC,
                         const float* __restrict__ Wm,
                         _Float16* __restrict__ pd0, _Float16* __restrict__ pm0,
                         _Float16* __restrict__ pd1, _Float16* __restrict__ pm1){
    int cfg = blockIdx.y;
    int layer = cfg >> 1;
    int isMix = cfg & 1;
    int count = isMix ? 16*8*64 : 18*8*64;
    int t = blockIdx.x*256 + threadIdx.x;
    if (t >= count) return;
    int lane = t & 63;
    int ks   = (t >> 6) & 7;
    int nt16 = t >> 9;
    int col  = nt16*16 + (lane & 15);
    int kb   = ks*32 + ((lane >> 4) << 3);
    const float* Wd_l = Wd + (size_t)layer*DM*DM;
    const float* WB_l = WB + (size_t)layer*DM*NS;
    const float* WC_l = WC + (size_t)layer*DM*NS;
    const float* Wm_l = Wm + (size_t)layer*DM*DM;
    f16x8 v;
    #pragma unroll
    for (int i=0;i<8;++i){
        float s;
        if (isMix)          s = Wm_l[(size_t)(kb+i)*DM + col];
        else if (col < 256) s = Wd_l[(size_t)(kb+i)*DM + col];
        else if (col < 272) s = WB_l[(size_t)(kb+i)*NS + (col-256)];
        else                s = WC_l[(size_t)(kb+i)*NS + (col-272)];
        v[i] = (_Float16)s;
    }
    _Float16* dst = isMix ? (layer ? pm1 : pm0) : (layer ? pd1 : pd0);
    ((f16x8*)dst)[t] = v;
}

// MFMA GEMM: [BL x 256] @ [256 x 288] -> dt(softplus+bias) | Bm | Cm
// 1 wave/block; block computes 32 rows x 32 cols; grid (BL/32, 9).
__global__ __launch_bounds__(64) void mfma_dtbc_k(const _Float16* __restrict__ xh,
                           const _Float16* __restrict__ wp,
                           const float* __restrict__ bd,
                           float* __restrict__ dt,
                           float* __restrict__ Bm,
                           float* __restrict__ Cm){
    int lane = threadIdx.x;
    int row0 = blockIdx.x*32;
    int nt2  = blockIdx.y;
    const f16x8* ah  = (const f16x8*)xh;
    const f16x8* wpb = (const f16x8*)wp;
    size_t a0i = (size_t)(row0 + (lane & 15))*32 + (lane >> 4);
    f32x4 acc[2][2] = {};
    #pragma unroll
    for (int ks=0; ks<8; ++ks){
        f16x8 a0 = ah[a0i + ks*4];
        f16x8 a1 = ah[a0i + 512 + ks*4];
        f16x8 b0 = wpb[((nt2*2    )*8 + ks)*64 + lane];
        f16x8 b1 = wpb[((nt2*2 + 1)*8 + ks)*64 + lane];
        acc[0][0] = __builtin_amdgcn_mfma_f32_16x16x32_f16(a0,b0,acc[0][0],0,0,0);
        acc[0][1] = __builtin_amdgcn_mfma_f32_16x16x32_f16(a0,b1,acc[0][1],0,0,0);
        acc[1][0] = __builtin_amdgcn_mfma_f32_16x16x32_f16(a1,b0,acc[1][0],0,0,0);
        acc[1][1] = __builtin_amdgcn_mfma_f32_16x16x32_f16(a1,b1,acc[1][1],0,0,0);
    }
    int c0 = nt2*32 + (lane & 15);
    int rb = row0 + ((lane >> 4) << 2);
    if (nt2 < 8){
        float bias0 = bd[c0], bias1 = bd[c0 + 16];
        #pragma unroll
        for (int mi=0; mi<2; ++mi){
            #pragma unroll
            for (int r=0; r<4; ++r){
                int grow = rb + mi*16 + r;
                dt[(size_t)grow*DM + c0]      = softplus_f(acc[mi][0][r] + bias0);
                dt[(size_t)grow*DM + c0 + 16] = softplus_f(acc[mi][1][r] + bias1);
            }
        }
    } else {
        int n = lane & 15;
        #pragma unroll
        for (int mi=0; mi<2; ++mi){
            #pragma unroll
            for (int r=0; r<4; ++r){
                int grow = rb + mi*16 + r;
                Bm[(size_t)grow*NS + n] = acc[mi][0][r];
                Cm[(size_t)grow*NS + n] = acc[mi][1][r];
            }
        }
    }
}

// MFMA GEMM: gelu'd f16 activations @ [256 x 256] + bias -> fp32 out.
__global__ __launch_bounds__(64) void mfma_mix_k(const _Float16* __restrict__ yh,
                          const _Float16* __restrict__ wp,
                          const float* __restrict__ bm,
                          float* __restrict__ out){
    int lane = threadIdx.x;
    int row0 = blockIdx.x*32;
    int nt2  = blockIdx.y;
    const f16x8* ah  = (const f16x8*)yh;
    const f16x8* wpb = (const f16x8*)wp;
    size_t a0i = (size_t)(row0 + (lane & 15))*32 + (lane >> 4);
    f32x4 acc[2][2] = {};
    #pragma unroll
    for (int ks=0; ks<8; ++ks){
        f16x8 a0 = ah[a0i + ks*4];
        f16x8 a1 = ah[a0i + 512 + ks*4];
        f16x8 b0 = wpb[((nt2*2    )*8 + ks)*64 + lane];
        f16x8 b1 = wpb[((nt2*2 + 1)*8 + ks)*64 + lane];
        acc[0][0] = __builtin_amdgcn_mfma_f32_16x16x32_f16(a0,b0,acc[0][0],0,0,0);
        acc[0][1] = __builtin_amdgcn_mfma_f32_16x16x32_f16(a0,b1,acc[0][1],0,0,0);
        acc[1][0] = __builtin_amdgcn_mfma_f32_16x16x32_f16(a1,b0,acc[1][0],0,0,0);
        acc[1][1] = __builtin_amdgcn_mfma_f32_16x16x32_f16(a1,b1,acc[1][1],0,0,0);
    }
    int c0 = nt2*32 + (lane & 15);
    int rb = row0 + ((lane >> 4) << 2);
    float bias0 = bm[c0], bias1 = bm[c0 + 16];
    #pragma unroll
    for (int mi=0; mi<2; ++mi){
        #pragma unroll
        for (int r=0; r<4; ++r){
            int grow = rb + mi*16 + r;
            out[(size_t)grow*DM + c0]      = acc[mi][0][r] + bias0;
            out[(size_t)grow*DM + c0 + 16] = acc[mi][1][r] + bias1;
        }
    }
}

__global__ __launch_bounds__(64) void scan_p1(const float* __restrict__ xn,
                        const float* __restrict__ dt,
                        const float* __restrict__ Bmv,
                        const float* __restrict__ A,
                        float* __restrict__ cA, float* __restrict__ cB){
    __shared__ float bs[CHUNK*NS];
    int lane = threadIdx.x;
    int c = blockIdx.x, dq = blockIdx.y, b = blockIdx.z;
    int d = dq*64 + lane;
    int row0 = b*LSEQ + c*CHUNK;
    {
        const float4* src = (const float4*)(Bmv + (size_t)row0*NS);
        float4* dst = (float4*)bs;
        #pragma unroll
        for (int i=0;i<(CHUNK*NS/4)/64;++i) dst[lane + 64*i] = src[lane + 64*i];
    }
    float Alg[NS];
    {
        const float4* ap = (const float4*)(A + (size_t)d*NS);
        #pragma unroll
        for (int q=0;q<4;++q){
            float4 av = ap[q];
            Alg[4*q+0]=av.x*LOG2E; Alg[4*q+1]=av.y*LOG2E;
            Alg[4*q+2]=av.z*LOG2E; Alg[4*q+3]=av.w*LOG2E;
        }
    }
    __syncthreads();
    float Ap[NS], Bp[NS];
    #pragma unroll
    for (int n=0;n<NS;++n){ Ap[n]=1.0f; Bp[n]=0.0f; }
    for (int tt=0; tt<CHUNK; ++tt){
        float dtv = dt[(size_t)(row0+tt)*DM + d];
        float xv  = xn[(size_t)(row0+tt)*DM + d];
        float dtx = dtv*xv;
        const float4* bp4 = (const float4*)&bs[tt*NS];
        #pragma unroll
        for (int q=0;q<4;++q){
            float4 bq = bp4[q];
            float bv[4] = {bq.x, bq.y, bq.z, bq.w};
            #pragma unroll
            for (int j=0;j<4;++j){
                int n = 4*q+j;
                float a = __builtin_amdgcn_exp2f(dtv*Alg[n]);
                Ap[n] *= a;
                Bp[n] = fmaf(a, Bp[n], dtx*bv[j]);
            }
        }
    }
    size_t base = (size_t)c*NCHAIN + ((size_t)b*DM + d)*NS;
    float4* pA = (float4*)(cA + base);
    float4* pB = (float4*)(cB + base);
    #pragma unroll
    for (int q=0;q<4;++q){
        pA[q] = make_float4(Ap[4*q],Ap[4*q+1],Ap[4*q+2],Ap[4*q+3]);
        pB[q] = make_float4(Bp[4*q],Bp[4*q+1],Bp[4*q+2],Bp[4*q+3]);
    }
}

__global__ __launch_bounds__(256) void scan_p2(const float* __restrict__ cA,
                        const float* __restrict__ cB,
                        float* __restrict__ hin){
    int chain = blockIdx.x*256 + threadIdx.x;
    float h = 0.0f;
    #pragma unroll 4
    for (int c=0;c<NCHUNK;++c){
        size_t idx = (size_t)c*NCHAIN + chain;
        hin[idx] = h;
        h = fmaf(cA[idx], h, cB[idx]);
    }
}

// Phase 3: replay chunk; y = sum_n h*C + D_skip*x; emit gelu(y) as f16 for mix GEMM.
__global__ __launch_bounds__(64) void scan_p3(const float* __restrict__ xn,
                        const float* __restrict__ dt,
                        const float* __restrict__ Bmv,
                        const float* __restrict__ Cmv,
                        const float* __restrict__ A,
                        const float* __restrict__ Dsk,
                        const float* __restrict__ hin,
                        _Float16* __restrict__ yh){
    __shared__ float bs[CHUNK*NS], cs[CHUNK*NS];
    int lane = threadIdx.x;
    int c = blockIdx.x, dq = blockIdx.y, b = blockIdx.z;
    int d = dq*64 + lane;
    int row0 = b*LSEQ + c*CHUNK;
    {
        const float4* srcB = (const float4*)(Bmv + (size_t)row0*NS);
        const float4* srcC = (const float4*)(Cmv + (size_t)row0*NS);
        float4* dstB = (float4*)bs;
        float4* dstC = (float4*)cs;
        #pragma unroll
        for (int i=0;i<(CHUNK*NS/4)/64;++i){
            dstB[lane + 64*i] = srcB[lane + 64*i];
            dstC[lane + 64*i] = srcC[lane + 64*i];
        }
    }
    float Alg[NS];
    {
        const float4* ap = (const float4*)(A + (size_t)d*NS);
        #pragma unroll
        for (int q=0;q<4;++q){
            float4 av = ap[q];
            Alg[4*q+0]=av.x*LOG2E; Alg[4*q+1]=av.y*LOG2E;
            Alg[4*q+2]=av.z*LOG2E; Alg[4*q+3]=av.w*LOG2E;
        }
    }
    float dsk = Dsk[d];
    float h[NS];
    {
        const float4* hp = (const float4*)(hin + (size_t)c*NCHAIN + ((size_t)b*DM + d)*NS);
        #pragma unroll
        for (int q=0;q<4;++q){
            float4 hv = hp[q];
            h[4*q+0]=hv.x; h[4*q+1]=hv.y; h[4*q+2]=hv.z; h[4*q+3]=hv.w;
        }
    }
    __syncthreads();
    for (int tt=0; tt<CHUNK; ++tt){
        float dtv = dt[(size_t)(row0+tt)*DM + d];
        float xv  = xn[(size_t)(row0+tt)*DM + d];
        float dtx = dtv*xv;
        float yacc = dsk*xv;
        const float4* bp4 = (const float4*)&bs[tt*NS];
        const float4* cp4 = (const float4*)&cs[tt*NS];
        #pragma unroll
        for (int q=0;q<4;++q){
            float4 bq = bp4[q];
            float4 cq = cp4[q];
            float bv[4] = {bq.x, bq.y, bq.z, bq.w};
            float cv[4] = {cq.x, cq.y, cq.z, cq.w};
            #pragma unroll
            for (int j=0;j<4;++j){
                int n = 4*q+j;
                float a = __builtin_amdgcn_exp2f(dtv*Alg[n]);
                h[n] = fmaf(a, h[n], dtx*bv[j]);
                yacc = fmaf(h[n], cv[j], yacc);
            }
        }
        yh[(size_t)(row0+tt)*DM + d] = (_Float16)gelu_f(yacc);
    }
}

extern "C" void kernel_launch(void* const* d_in, const int* in_sizes, int n_in,
                              void* d_out, int out_size, void* d_ws, size_t ws_size,
                              hipStream_t stream) {
    const float* x  = (const float*)d_in[0];
    const float* A  = (const float*)d_in[1];
    const float* Wd = (const float*)d_in[2];
    const float* bd = (const float*)d_in[3];
    const float* WB = (const float*)d_in[4];
    const float* WC = (const float*)d_in[5];
    const float* Ds = (const float*)d_in[6];
    const float* Wm = (const float*)d_in[7];
    const float* bm = (const float*)d_in[8];
    float* out = (float*)d_out;

    const size_t BSZ = (size_t)BL*DM;          // 2,097,152 floats
    const size_t CH  = (size_t)NCHUNK*NCHAIN;  // 1,048,576 floats
    float* ws  = (float*)d_ws;
    float* b0  = ws;
    float* b1  = b0  + BSZ;
    float* b2  = b1  + BSZ;
    float* Bmb = b2  + BSZ;
    float* Cmb = Bmb + (size_t)BL*NS;
    float* cA  = Cmb + (size_t)BL*NS;
    float* cB  = cA  + CH;
    float* hin = cB  + CH;
    _Float16* packs = (_Float16*)(hin + CH);
    _Float16* pd0 = packs;                 // 18*8*64*8 = 73728
    _Float16* pd1 = pd0 + 73728;
    _Float16* pm0 = pd1 + 73728;           // 16*8*64*8 = 65536
    _Float16* pm1 = pm0 + 65536;
    _Float16* xh = (_Float16*)cA;          // f16 activations (dead before cA written)
    _Float16* yh = (_Float16*)cB;          // f16 gelu'd scan out (dead before... cB read done)

    dim3 gs(NCHUNK, DM/64, BATCH);
    dim3 gdt(BL/32, 9);
    dim3 gmx(BL/32, 8);

    pack_w_k<<<dim3(36,4), 256, 0, stream>>>(Wd, WB, WC, Wm, pd0, pm0, pd1, pm1);

    // ---- layer 0 ----
    rmsnorm_k<<<BL/4, 256, 0, stream>>>(x, b0, xh);
    mfma_dtbc_k<<<gdt, 64, 0, stream>>>(xh, pd0, bd, b1, Bmb, Cmb);
    scan_p1<<<gs, 64, 0, stream>>>(b0, b1, Bmb, A, cA, cB);
    scan_p2<<<NCHAIN/256, 256, 0, stream>>>(cA, cB, hin);
    scan_p3<<<gs, 64, 0, stream>>>(b0, b1, Bmb, Cmb, A, Ds, hin, yh);
    mfma_mix_k<<<gmx, 64, 0, stream>>>(yh, pm0, bm, b0);

    // ---- layer 1 ----
    const float* A1  = A  + (size_t)DM*NS;
    const float* bd1 = bd + DM;
    const float* Ds1 = Ds + DM;
    const float* bm1 = bm + DM;
    rmsnorm_k<<<BL/4, 256, 0, stream>>>(b0, b1, xh);
    mfma_dtbc_k<<<gdt, 64, 0, stream>>>(xh, pd1, bd1, b2, Bmb, Cmb);
    scan_p1<<<gs, 64, 0, stream>>>(b1, b2, Bmb, A1, cA, cB);
    scan_p2<<<NCHAIN/256, 256, 0, stream>>>(cA, cB, hin);
    scan_p3<<<gs, 64, 0, stream>>>(b1, b2, Bmb, Cmb, A1, Ds1, hin, yh);
    mfma_mix_k<<<gmx, 64, 0, stream>>>(yh, pm1, bm1, b0);

    // ---- final norm ----
    rmsnorm_k<<<BL/4, 256, 0, stream>>>(b0, out, (_Float16*)0);
}

// Round 4
// 207.526 us; speedup vs baseline: 1.6060x; 1.1329x over previous
//
#include <hip/hip_runtime.h>
#include <hip/hip_bf16.h>

#define BATCH 2
#define LSEQ 4096
#define DM 256
#define NS 16
#define BL (BATCH*LSEQ)
#define CHUNK 32
#define NCHUNK (LSEQ/CHUNK)     // 128
#define NCHAIN (BATCH*DM*NS)    // 8192
#define LOG2E 1.4426950408889634f

typedef _Float16 f16x8 __attribute__((ext_vector_type(8)));
typedef _Float16 f16x4 __attribute__((ext_vector_type(4)));
typedef float f32x4 __attribute__((ext_vector_type(4)));

__device__ __forceinline__ float softplus_f(float z){
    return fmaxf(z, 0.0f) + log1pf(__expf(-fabsf(z)));
}
__device__ __forceinline__ float gelu_f(float x){
    float u = 0.7978845608028654f*(x + 0.044715f*x*x*x);
    float e = __builtin_amdgcn_exp2f(2.0f*LOG2E*u);
    float th = 1.0f - 2.0f*__builtin_amdgcn_rcpf(e + 1.0f);
    return 0.5f*x*(1.0f + th);
}

// RMSNorm; optionally also emit an f16 copy for the MFMA GEMM A-operand.
__global__ __launch_bounds__(256) void rmsnorm_k(const float* __restrict__ in,
                                                 float* __restrict__ out,
                                                 _Float16* __restrict__ outh){
    int lane = threadIdx.x & 63;
    int wv   = threadIdx.x >> 6;
    int row  = blockIdx.x*4 + wv;
    const float4* rin = (const float4*)(in + (size_t)row*DM);
    float4 v = rin[lane];
    float ss = v.x*v.x + v.y*v.y + v.z*v.z + v.w*v.w;
    #pragma unroll
    for (int off=32; off>=1; off>>=1) ss += __shfl_xor(ss, off, 64);
    float s = rsqrtf(ss*(1.0f/DM) + 1.1920929e-07f);
    float4 o; o.x=v.x*s; o.y=v.y*s; o.z=v.z*s; o.w=v.w*s;
    ((float4*)(out + (size_t)row*DM))[lane] = o;
    if (outh){
        f16x4 h; h[0]=(_Float16)o.x; h[1]=(_Float16)o.y; h[2]=(_Float16)o.z; h[3]=(_Float16)o.w;
        *(f16x4*)(outh + (size_t)row*DM + lane*4) = h;
    }
}

// Pack weights (fp32 -> f16) into MFMA B-fragment order.
__global__ __launch_bounds__(256) void pack_w_k(const float* __restrict__ Wd,
                         const float* __restrict__ WB,
                         const float* __restrict__ WC,
                         const float* __restrict__ Wm,
                         _Float16* __restrict__ pd0, _Float16* __restrict__ pm0,
                         _Float16* __restrict__ pd1, _Float16* __restrict__ pm1){
    int cfg = blockIdx.y;
    int layer = cfg >> 1;
    int isMix = cfg & 1;
    int count = isMix ? 16*8*64 : 18*8*64;
    int t = blockIdx.x*256 + threadIdx.x;
    if (t >= count) return;
    int lane = t & 63;
    int ks   = (t >> 6) & 7;
    int nt16 = t >> 9;
    int col  = nt16*16 + (lane & 15);
    int kb   = ks*32 + ((lane >> 4) << 3);
    const float* Wd_l = Wd + (size_t)layer*DM*DM;
    const float* WB_l = WB + (size_t)layer*DM*NS;
    const float* WC_l = WC + (size_t)layer*DM*NS;
    const float* Wm_l = Wm + (size_t)layer*DM*DM;
    f16x8 v;
    #pragma unroll
    for (int i=0;i<8;++i){
        float s;
        if (isMix)          s = Wm_l[(size_t)(kb+i)*DM + col];
        else if (col < 256) s = Wd_l[(size_t)(kb+i)*DM + col];
        else if (col < 272) s = WB_l[(size_t)(kb+i)*NS + (col-256)];
        else                s = WC_l[(size_t)(kb+i)*NS + (col-272)];
        v[i] = (_Float16)s;
    }
    _Float16* dst = isMix ? (layer ? pm1 : pm0) : (layer ? pd1 : pd0);
    ((f16x8*)dst)[t] = v;
}

// MFMA GEMM: [BL x 256] @ [256 x 288] -> dt(softplus+bias) | Bm | Cm
__global__ __launch_bounds__(64) void mfma_dtbc_k(const _Float16* __restrict__ xh,
                           const _Float16* __restrict__ wp,
                           const float* __restrict__ bd,
                           float* __restrict__ dt,
                           float* __restrict__ Bm,
                           float* __restrict__ Cm){
    int lane = threadIdx.x;
    int row0 = blockIdx.x*32;
    int nt2  = blockIdx.y;
    const f16x8* ah  = (const f16x8*)xh;
    const f16x8* wpb = (const f16x8*)wp;
    size_t a0i = (size_t)(row0 + (lane & 15))*32 + (lane >> 4);
    f32x4 acc[2][2] = {};
    #pragma unroll
    for (int ks=0; ks<8; ++ks){
        f16x8 a0 = ah[a0i + ks*4];
        f16x8 a1 = ah[a0i + 512 + ks*4];
        f16x8 b0 = wpb[((nt2*2    )*8 + ks)*64 + lane];
        f16x8 b1 = wpb[((nt2*2 + 1)*8 + ks)*64 + lane];
        acc[0][0] = __builtin_amdgcn_mfma_f32_16x16x32_f16(a0,b0,acc[0][0],0,0,0);
        acc[0][1] = __builtin_amdgcn_mfma_f32_16x16x32_f16(a0,b1,acc[0][1],0,0,0);
        acc[1][0] = __builtin_amdgcn_mfma_f32_16x16x32_f16(a1,b0,acc[1][0],0,0,0);
        acc[1][1] = __builtin_amdgcn_mfma_f32_16x16x32_f16(a1,b1,acc[1][1],0,0,0);
    }
    int c0 = nt2*32 + (lane & 15);
    int rb = row0 + ((lane >> 4) << 2);
    if (nt2 < 8){
        float bias0 = bd[c0], bias1 = bd[c0 + 16];
        #pragma unroll
        for (int mi=0; mi<2; ++mi){
            #pragma unroll
            for (int r=0; r<4; ++r){
                int grow = rb + mi*16 + r;
                dt[(size_t)grow*DM + c0]      = softplus_f(acc[mi][0][r] + bias0);
                dt[(size_t)grow*DM + c0 + 16] = softplus_f(acc[mi][1][r] + bias1);
            }
        }
    } else {
        int n = lane & 15;
        #pragma unroll
        for (int mi=0; mi<2; ++mi){
            #pragma unroll
            for (int r=0; r<4; ++r){
                int grow = rb + mi*16 + r;
                Bm[(size_t)grow*NS + n] = acc[mi][0][r];
                Cm[(size_t)grow*NS + n] = acc[mi][1][r];
            }
        }
    }
}

// MFMA GEMM: gelu'd f16 activations @ [256 x 256] + bias -> fp32 out.
__global__ __launch_bounds__(64) void mfma_mix_k(const _Float16* __restrict__ yh,
                          const _Float16* __restrict__ wp,
                          const float* __restrict__ bm,
                          float* __restrict__ out){
    int lane = threadIdx.x;
    int row0 = blockIdx.x*32;
    int nt2  = blockIdx.y;
    const f16x8* ah  = (const f16x8*)yh;
    const f16x8* wpb = (const f16x8*)wp;
    size_t a0i = (size_t)(row0 + (lane & 15))*32 + (lane >> 4);
    f32x4 acc[2][2] = {};
    #pragma unroll
    for (int ks=0; ks<8; ++ks){
        f16x8 a0 = ah[a0i + ks*4];
        f16x8 a1 = ah[a0i + 512 + ks*4];
        f16x8 b0 = wpb[((nt2*2    )*8 + ks)*64 + lane];
        f16x8 b1 = wpb[((nt2*2 + 1)*8 + ks)*64 + lane];
        acc[0][0] = __builtin_amdgcn_mfma_f32_16x16x32_f16(a0,b0,acc[0][0],0,0,0);
        acc[0][1] = __builtin_amdgcn_mfma_f32_16x16x32_f16(a0,b1,acc[0][1],0,0,0);
        acc[1][0] = __builtin_amdgcn_mfma_f32_16x16x32_f16(a1,b0,acc[1][0],0,0,0);
        acc[1][1] = __builtin_amdgcn_mfma_f32_16x16x32_f16(a1,b1,acc[1][1],0,0,0);
    }
    int c0 = nt2*32 + (lane & 15);
    int rb = row0 + ((lane >> 4) << 2);
    float bias0 = bm[c0], bias1 = bm[c0 + 16];
    #pragma unroll
    for (int mi=0; mi<2; ++mi){
        #pragma unroll
        for (int r=0; r<4; ++r){
            int grow = rb + mi*16 + r;
            out[(size_t)grow*DM + c0]      = acc[mi][0][r] + bias0;
            out[(size_t)grow*DM + c0 + 16] = acc[mi][1][r] + bias1;
        }
    }
}

// Scan phase 1: 256 threads = 64 d's x 4 n-quads. grid (NCHUNK, DM/64, BATCH).
__global__ __launch_bounds__(256) void scan_p1(const float* __restrict__ xn,
                        const float* __restrict__ dt,
                        const float* __restrict__ Bmv,
                        const float* __restrict__ A,
                        float* __restrict__ cA, float* __restrict__ cB){
    __shared__ float4 bs[CHUNK*4];
    int tid = threadIdx.x;
    int c = blockIdx.x, dq = blockIdx.y, b = blockIdx.z;
    int dl = tid >> 2, nq = tid & 3;
    int d  = dq*64 + dl;
    int row0 = b*LSEQ + c*CHUNK;
    if (tid < CHUNK*4) bs[tid] = ((const float4*)(Bmv + (size_t)row0*NS))[tid];
    float4 Alg = ((const float4*)(A + (size_t)d*NS))[nq];
    Alg.x *= LOG2E; Alg.y *= LOG2E; Alg.z *= LOG2E; Alg.w *= LOG2E;
    __syncthreads();
    float Ap0=1,Ap1=1,Ap2=1,Ap3=1, Bp0=0,Bp1=0,Bp2=0,Bp3=0;
    #pragma unroll 4
    for (int tt=0; tt<CHUNK; ++tt){
        float dtv = dt[(size_t)(row0+tt)*DM + d];
        float xv  = xn[(size_t)(row0+tt)*DM + d];
        float dtx = dtv*xv;
        float4 bq = bs[tt*4 + nq];
        float a0 = __builtin_amdgcn_exp2f(dtv*Alg.x);
        float a1 = __builtin_amdgcn_exp2f(dtv*Alg.y);
        float a2 = __builtin_amdgcn_exp2f(dtv*Alg.z);
        float a3 = __builtin_amdgcn_exp2f(dtv*Alg.w);
        Ap0 *= a0; Bp0 = fmaf(a0, Bp0, dtx*bq.x);
        Ap1 *= a1; Bp1 = fmaf(a1, Bp1, dtx*bq.y);
        Ap2 *= a2; Bp2 = fmaf(a2, Bp2, dtx*bq.z);
        Ap3 *= a3; Bp3 = fmaf(a3, Bp3, dtx*bq.w);
    }
    size_t base = (size_t)c*NCHAIN + ((size_t)b*DM + d)*NS + nq*4;
    *(float4*)(cA + base) = make_float4(Ap0,Ap1,Ap2,Ap3);
    *(float4*)(cB + base) = make_float4(Bp0,Bp1,Bp2,Bp3);
}

// Phase 2: sequential scan across chunks. 128 blocks x 64 threads.
__global__ __launch_bounds__(64) void scan_p2(const float* __restrict__ cA,
                        const float* __restrict__ cB,
                        float* __restrict__ hin){
    int chain = blockIdx.x*64 + threadIdx.x;
    float h = 0.0f;
    #pragma unroll 8
    for (int c=0;c<NCHUNK;++c){
        size_t idx = (size_t)c*NCHAIN + chain;
        hin[idx] = h;
        h = fmaf(cA[idx], h, cB[idx]);
    }
}

// Phase 3: replay with correct h_in; y = sum_n h*C + D_skip*x; emit gelu(y) f16.
__global__ __launch_bounds__(256) void scan_p3(const float* __restrict__ xn,
                        const float* __restrict__ dt,
                        const float* __restrict__ Bmv,
                        const float* __restrict__ Cmv,
                        const float* __restrict__ A,
                        const float* __restrict__ Dsk,
                        const float* __restrict__ hin,
                        _Float16* __restrict__ yh){
    __shared__ float4 bs[CHUNK*4], cs[CHUNK*4];
    int tid = threadIdx.x;
    int c = blockIdx.x, dq = blockIdx.y, b = blockIdx.z;
    int dl = tid >> 2, nq = tid & 3;
    int d  = dq*64 + dl;
    int row0 = b*LSEQ + c*CHUNK;
    if (tid < CHUNK*4){
        bs[tid] = ((const float4*)(Bmv + (size_t)row0*NS))[tid];
        cs[tid] = ((const float4*)(Cmv + (size_t)row0*NS))[tid];
    }
    float4 Alg = ((const float4*)(A + (size_t)d*NS))[nq];
    Alg.x *= LOG2E; Alg.y *= LOG2E; Alg.z *= LOG2E; Alg.w *= LOG2E;
    float dsk = Dsk[d];
    float4 hv = ((const float4*)(hin + (size_t)c*NCHAIN + ((size_t)b*DM + d)*NS))[nq];
    float h0=hv.x, h1=hv.y, h2=hv.z, h3=hv.w;
    __syncthreads();
    #pragma unroll 4
    for (int tt=0; tt<CHUNK; ++tt){
        float dtv = dt[(size_t)(row0+tt)*DM + d];
        float xv  = xn[(size_t)(row0+tt)*DM + d];
        float dtx = dtv*xv;
        float4 bq = bs[tt*4 + nq];
        float4 cq = cs[tt*4 + nq];
        float a0 = __builtin_amdgcn_exp2f(dtv*Alg.x);
        float a1 = __builtin_amdgcn_exp2f(dtv*Alg.y);
        float a2 = __builtin_amdgcn_exp2f(dtv*Alg.z);
        float a3 = __builtin_amdgcn_exp2f(dtv*Alg.w);
        h0 = fmaf(a0, h0, dtx*bq.x);
        h1 = fmaf(a1, h1, dtx*bq.y);
        h2 = fmaf(a2, h2, dtx*bq.z);
        h3 = fmaf(a3, h3, dtx*bq.w);
        float p = fmaf(h0, cq.x, fmaf(h1, cq.y, fmaf(h2, cq.z, h3*cq.w)));
        p += __shfl_xor(p, 1, 64);
        p += __shfl_xor(p, 2, 64);
        if (nq == 0){
            float yv = p + dsk*xv;
            yh[(size_t)(row0+tt)*DM + d] = (_Float16)gelu_f(yv);
        }
    }
}

extern "C" void kernel_launch(void* const* d_in, const int* in_sizes, int n_in,
                              void* d_out, int out_size, void* d_ws, size_t ws_size,
                              hipStream_t stream) {
    const float* x  = (const float*)d_in[0];
    const float* A  = (const float*)d_in[1];
    const float* Wd = (const float*)d_in[2];
    const float* bd = (const float*)d_in[3];
    const float* WB = (const float*)d_in[4];
    const float* WC = (const float*)d_in[5];
    const float* Ds = (const float*)d_in[6];
    const float* Wm = (const float*)d_in[7];
    const float* bm = (const float*)d_in[8];
    float* out = (float*)d_out;

    const size_t BSZ = (size_t)BL*DM;          // 2,097,152 floats
    const size_t CH  = (size_t)NCHUNK*NCHAIN;  // 1,048,576 floats
    float* ws  = (float*)d_ws;
    float* b0  = ws;
    float* b1  = b0  + BSZ;
    float* b2  = b1  + BSZ;
    float* Bmb = b2  + BSZ;
    float* Cmb = Bmb + (size_t)BL*NS;
    float* cA  = Cmb + (size_t)BL*NS;
    float* cB  = cA  + CH;
    float* hin = cB  + CH;
    _Float16* packs = (_Float16*)(hin + CH);
    _Float16* pd0 = packs;
    _Float16* pd1 = pd0 + 73728;
    _Float16* pm0 = pd1 + 73728;
    _Float16* pm1 = pm0 + 65536;
    _Float16* xh = (_Float16*)cA;   // aliased: dead before cA written
    _Float16* yh = (_Float16*)cB;   // aliased: cB dead (post-p2) when p3 writes yh

    dim3 gs(NCHUNK, DM/64, BATCH);
    dim3 gdt(BL/32, 9);
    dim3 gmx(BL/32, 8);

    pack_w_k<<<dim3(36,4), 256, 0, stream>>>(Wd, WB, WC, Wm, pd0, pm0, pd1, pm1);

    // ---- layer 0 ----
    rmsnorm_k<<<BL/4, 256, 0, stream>>>(x, b0, xh);
    mfma_dtbc_k<<<gdt, 64, 0, stream>>>(xh, pd0, bd, b1, Bmb, Cmb);
    scan_p1<<<gs, 256, 0, stream>>>(b0, b1, Bmb, A, cA, cB);
    scan_p2<<<NCHAIN/64, 64, 0, stream>>>(cA, cB, hin);
    scan_p3<<<gs, 256, 0, stream>>>(b0, b1, Bmb, Cmb, A, Ds, hin, yh);
    mfma_mix_k<<<gmx, 64, 0, stream>>>(yh, pm0, bm, b0);

    // ---- layer 1 ----
    const float* A1  = A  + (size_t)DM*NS;
    const float* bd1 = bd + DM;
    const float* Ds1 = Ds + DM;
    const float* bm1 = bm + DM;
    rmsnorm_k<<<BL/4, 256, 0, stream>>>(b0, b1, xh);
    mfma_dtbc_k<<<gdt, 64, 0, stream>>>(xh, pd1, bd1, b2, Bmb, Cmb);
    scan_p1<<<gs, 256, 0, stream>>>(b1, b2, Bmb, A1, cA, cB);
    scan_p2<<<NCHAIN/64, 64, 0, stream>>>(cA, cB, hin);
    scan_p3<<<gs, 256, 0, stream>>>(b1, b2, Bmb, Cmb, A1, Ds1, hin, yh);
    mfma_mix_k<<<gmx, 64, 0, stream>>>(yh, pm1, bm1, b0);

    // ---- final norm ----
    rmsnorm_k<<<BL/4, 256, 0, stream>>>(b0, out, (_Float16*)0);
}